// Round 17
// baseline (124.303 us; speedup 1.0000x reference)
//
#include <hip/hip_runtime.h>

// Workspace layout (40 MB total):
//   [0,  8M)  Xb  bf16 [4096][1024]   (reused as Yb after QKV GEMM)
//   [8, 14M)  Wkqv_t bf16 [3072][1024]
//   [14,16M)  Wproj_t bf16 [1024][1024]
//   [16,24M)  Qb bf16 [B,H,T,D]  (pre-scaled by 0.125*log2e)
//   [24,32M)  Kb bf16 [B,H,T,D]
//   [32,40M)  Vb bf16 [B,H,T,D]

#define DEVI __device__ __forceinline__

typedef unsigned short ushort_t;
typedef unsigned long long u64_t;
typedef __attribute__((ext_vector_type(4))) unsigned short us4;
typedef __attribute__((ext_vector_type(8))) unsigned short ushort8;
typedef __attribute__((ext_vector_type(4))) float f32x4;
typedef __attribute__((ext_vector_type(8))) __bf16 bf16x8;

DEVI unsigned short f2bf(float f) {
  union { float f; unsigned int u; } c; c.f = f;
  unsigned int u = c.u;
  unsigned int r = (u + 0x7FFFu + ((u >> 16) & 1u)) >> 16;
  return (unsigned short)r;
}

// exp2 via raw v_exp_f32 (1 VALU trans op; s_nop covers the RAW hazard)
DEVI float exp2v(float x) {
  float r;
  asm("v_exp_f32 %0, %1\n\ts_nop 0" : "=v"(r) : "v"(x));
  return r;
}

// pack 2 fp32 -> 2 bf16 (RNE) in one instruction
DEVI unsigned int cvtpk(float lo, float hi) {
  unsigned int r;
  asm("v_cvt_pk_bf16_f32 %0, %1, %2" : "=v"(r) : "v"(lo), "v"(hi));
  return r;
}

DEVI f32x4 mfma16(ushort8 a, ushort8 b, f32x4 c) {
  return __builtin_amdgcn_mfma_f32_16x16x32_bf16(
      __builtin_bit_cast(bf16x8, a), __builtin_bit_cast(bf16x8, b), c, 0, 0, 0);
}

typedef const __attribute__((address_space(1))) void* gptr_t;
typedef __attribute__((address_space(3))) void* lptr_t;
#define GLOAD_LDS16(g, l) \
  __builtin_amdgcn_global_load_lds((gptr_t)(g), (lptr_t)(l), 16, 0, 0)

DEVI void bar() {
  asm volatile("" ::: "memory");
  __builtin_amdgcn_s_barrier();
  asm volatile("" ::: "memory");
}
#define VMCNT(n) asm volatile("s_waitcnt vmcnt(" #n ")" ::: "memory")

// ---------------- fused prep kernel ----------------
// blocks [0,2048): cast x -> Xb (bf16)
// blocks [2048,5120): transpose+cast W_kqv -> Wkt [3072][1024]
// blocks [5120,6144): transpose+cast W_proj -> Wpt [1024][1024]

__global__ void prep_kernel(const float* __restrict__ x,
                            const float* __restrict__ Wk,
                            const float* __restrict__ Wp,
                            ushort_t* __restrict__ Xb,
                            ushort_t* __restrict__ Wkt,
                            ushort_t* __restrict__ Wpt) {
  __shared__ float tile[32][33];
  const int id = blockIdx.x, tid = threadIdx.x;
  if (id < 2048) {
    const int i = id * 256 + tid;
    const f32x4* p = (const f32x4*)x;
    f32x4 a = p[2 * i], b = p[2 * i + 1];
    ushort8 o;
    o[0] = f2bf(a[0]); o[1] = f2bf(a[1]); o[2] = f2bf(a[2]); o[3] = f2bf(a[3]);
    o[4] = f2bf(b[0]); o[5] = f2bf(b[1]); o[6] = f2bf(b[2]); o[7] = f2bf(b[3]);
    ((ushort8*)Xb)[i] = o;
    return;
  }
  const float* in;
  ushort_t* outp;
  int R = 1024, Cin, bx, by;
  if (id < 5120) {
    const int jid = id - 2048;
    bx = jid % 96; by = jid / 96; in = Wk; outp = Wkt; Cin = 3072;
  } else {
    const int jid = id - 5120;
    bx = jid % 32; by = jid / 32; in = Wp; outp = Wpt; Cin = 1024;
  }
  const int c0 = bx * 32, r0 = by * 32;
  const int tx = tid & 31, ty = tid >> 5;
#pragma unroll
  for (int it = 0; it < 4; ++it)
    tile[ty + it * 8][tx] = in[(size_t)(r0 + ty + it * 8) * Cin + c0 + tx];
  __syncthreads();
#pragma unroll
  for (int it = 0; it < 4; ++it)
    outp[(size_t)(c0 + ty + it * 8) * R + r0 + tx] = f2bf(tile[tx][ty + it * 8]);
}

// ---------------- QKV GEMM: 128x128, m97 structure ----------------
// XCD mapping: by-fast chunked -> per-XCD working set L2-resident.

__global__ __launch_bounds__(256) void gemm_bt_kernel(
    const ushort_t* __restrict__ A, const ushort_t* __restrict__ Bt,
    const float* __restrict__ bias, float* __restrict__ outF,
    float* __restrict__ outK, float* __restrict__ outV,
    ushort_t* __restrict__ Qb, ushort_t* __restrict__ Kb, ushort_t* __restrict__ Vb,
    int M, int N, int K, int mode) {
  __shared__ __align__(16) ushort_t As[128 * 64];
  __shared__ __align__(16) ushort_t Bs[128 * 64];
  const int tid = threadIdx.x;
  const int w = tid >> 6, lane = tid & 63;
  const int wr = w >> 1, wc = w & 1;
  const int nby = gridDim.y;
  const int chy = nby >> 3;
  const int orig = blockIdx.x + gridDim.x * blockIdx.y;
  const int xcd = orig & 7, idx = orig >> 3;
  const int by = xcd * chy + (idx % chy);
  const int bx = idx / chy;
  const int m0 = by * 128, n0 = bx * 128;
  const int l15 = lane & 15, lhi = lane >> 4;
  const int rowA = lane >> 3;
  const int sgc = (((lane & 7) ^ ((lane >> 3) & 7)) << 3);

  f32x4 acc[4][4] = {};

  const int nk = K >> 6;
  for (int kt = 0; kt < nk; ++kt) {
    const size_t k0 = (size_t)kt << 6;
    if (kt) bar();
#pragma unroll
    for (int it = 0; it < 4; ++it) {
      const int rbase = (w * 4 + it) * 8;
      GLOAD_LDS16(A + (size_t)(m0 + rbase + rowA) * K + k0 + sgc, &As[rbase * 64]);
      GLOAD_LDS16(Bt + (size_t)(n0 + rbase + rowA) * K + k0 + sgc, &Bs[rbase * 64]);
    }
    VMCNT(0);
    bar();
#pragma unroll
    for (int kk = 0; kk < 2; ++kk) {
      const int gof = (((kk * 4 + lhi) ^ (l15 & 7)) << 3);
      ushort8 a[4], b[4];
#pragma unroll
      for (int i = 0; i < 4; ++i)
        a[i] = *(const ushort8*)&As[(wr * 64 + i * 16 + l15) * 64 + gof];
#pragma unroll
      for (int j = 0; j < 4; ++j)
        b[j] = *(const ushort8*)&Bs[(wc * 64 + j * 16 + l15) * 64 + gof];
#pragma unroll
      for (int i = 0; i < 4; ++i)
#pragma unroll
        for (int j = 0; j < 4; ++j) acc[i][j] = mfma16(a[i], b[j], acc[i][j]);
    }
  }

  const float QSCALE = 0.18033688011112042f;  // 0.125 * log2(e)
#pragma unroll
  for (int i = 0; i < 4; ++i) {
#pragma unroll
    for (int j = 0; j < 4; ++j) {
      const int nn = n0 + wc * 64 + j * 16 + l15;
      const float bv = bias[nn];
#pragma unroll
      for (int r = 0; r < 4; ++r) {
        const int mm = m0 + wr * 64 + i * 16 + lhi * 4 + r;
        const float v = acc[i][j][r] + bv;
        if (mode == 0) {
          outF[(size_t)mm * N + nn] = v;
        } else {
          const int bb = mm >> 11, t = mm & 2047;
          const int c = nn & 1023, h = c >> 6, d = c & 63;
          const size_t idx2 = ((size_t)(bb * 16 + h) * 2048 + t) * 64 + d;
          const int sec = nn >> 10;
          if (sec == 0) {
            Qb[idx2] = f2bf(v * QSCALE);
          } else if (sec == 1) {
            outK[idx2] = v; Kb[idx2] = f2bf(v);
          } else {
            outV[idx2] = v; Vb[idx2] = f2bf(v);
          }
        }
      }
    }
  }
}

// ---------------- proj GEMM: 64x128 tiles, same chunked XCD mapping ----------------

__global__ __launch_bounds__(256) void gemm_bt64_kernel(
    const ushort_t* __restrict__ A, const ushort_t* __restrict__ Bt,
    const float* __restrict__ bias, float* __restrict__ outF,
    int M, int N, int K) {
  __shared__ __align__(16) ushort_t As[64 * 64];
  __shared__ __align__(16) ushort_t Bs[128 * 64];
  const int tid = threadIdx.x;
  const int w = tid >> 6, lane = tid & 63;
  const int wr = w >> 1, wc = w & 1;
  const int nby = gridDim.y;
  const int chy = nby >> 3;
  const int orig = blockIdx.x + gridDim.x * blockIdx.y;
  const int xcd = orig & 7, idx = orig >> 3;
  const int by = xcd * chy + (idx % chy);
  const int bx = idx / chy;
  const int m0 = by * 64, n0 = bx * 128;
  const int l15 = lane & 15, lhi = lane >> 4;
  const int rowA = lane >> 3;
  const int sgc = (((lane & 7) ^ ((lane >> 3) & 7)) << 3);

  f32x4 acc[2][4] = {};

  const int nk = K >> 6;
  for (int kt = 0; kt < nk; ++kt) {
    const size_t k0 = (size_t)kt << 6;
    if (kt) bar();
#pragma unroll
    for (int it = 0; it < 2; ++it) {
      const int rbase = (w * 2 + it) * 8;  // A: 64 rows
      GLOAD_LDS16(A + (size_t)(m0 + rbase + rowA) * K + k0 + sgc, &As[rbase * 64]);
    }
#pragma unroll
    for (int it = 0; it < 4; ++it) {
      const int rbase = (w * 4 + it) * 8;  // B: 128 rows
      GLOAD_LDS16(Bt + (size_t)(n0 + rbase + rowA) * K + k0 + sgc, &Bs[rbase * 64]);
    }
    VMCNT(0);
    bar();
#pragma unroll
    for (int kk = 0; kk < 2; ++kk) {
      const int gof = (((kk * 4 + lhi) ^ (l15 & 7)) << 3);
      ushort8 a[2], b[4];
#pragma unroll
      for (int i = 0; i < 2; ++i)
        a[i] = *(const ushort8*)&As[(wr * 32 + i * 16 + l15) * 64 + gof];
#pragma unroll
      for (int j = 0; j < 4; ++j)
        b[j] = *(const ushort8*)&Bs[(wc * 64 + j * 16 + l15) * 64 + gof];
#pragma unroll
      for (int i = 0; i < 2; ++i)
#pragma unroll
        for (int j = 0; j < 4; ++j) acc[i][j] = mfma16(a[i], b[j], acc[i][j]);
    }
  }

#pragma unroll
  for (int i = 0; i < 2; ++i) {
#pragma unroll
    for (int j = 0; j < 4; ++j) {
      const int nn = n0 + wc * 64 + j * 16 + l15;
      const float bv = bias[nn];
#pragma unroll
      for (int r = 0; r < 4; ++r) {
        const int mm = m0 + wr * 32 + i * 16 + lhi * 4 + r;
        outF[(size_t)mm * N + nn] = acc[i][j][r] + bv;
      }
    }
  }
}

// ---------------- flash attention: 4 waves x 32 q-rows (2 q-frags/wave) ----------------
// Grid 512 x 256 threads. XCD-pinned (bh%8 == id%8), balanced-pair dispatch.
// Shared kb/vb reads serve both q-frags -> K/Vt LDS read traffic halves.
// Vt swizzle key = (d>>2)&7 (was d>>3): kills the 8-way b32-write conflict
// (d-stride 144B = 16 banks; key must vary with d>>2 to spread writes).

__global__ __launch_bounds__(256) void attn_kernel(
    const ushort_t* __restrict__ Qb, const ushort_t* __restrict__ Kb,
    const ushort_t* __restrict__ Vb, ushort_t* __restrict__ Yb) {
  __shared__ __align__(16) ushort_t Ks[2][64 * 64];   // K [t][d], chunk-swizzled
  __shared__ __align__(16) ushort_t Vt[2][64 * 72];   // V^T [d][t], swizzled (d>>2 key)
  __shared__ __align__(16) ushort_t Pl[8 * 16 * 72];  // per-(wave,qg) P^T' [q][t]
  const int id = blockIdx.x;
  const int xcd = id & 7;
  int qt, bh;
  if (id < 256) {
    const int j = id >> 3;
    bh = xcd + 8 * (j & 3);
    qt = 8 + (j >> 2);                // 8..15
  } else {
    const int j = (id - 256) >> 3;
    bh = xcd + 8 * (j & 3);
    qt = 7 - (j >> 2);                // 7..0
  }
  const int b = bh >> 4, h = bh & 15;
  const int tid = threadIdx.x, w = tid >> 6, lane = tid & 63;
  const int l15 = lane & 15, lhi = lane >> 4;
  const int swzP = 2 * (l15 & 3);
  const size_t base = (size_t)bh * 2048 * 64;
  const float NEG_INF = -__builtin_inff();
  ushort_t* myP = &Pl[w * 2 * 16 * 72];  // [qg][16][72]

  // K staging: two 16B chunks per thread (512 chunks = 64x64 tile)
  // V staging: per it: rows t0,t0+1 x 4 d's per thread
  const int vd0 = (tid & 15) * 4;
  const int vt0b = (tid >> 4) * 2;

  const int nkt = 2 * qt + 2;

  // Q fragments (B-operand) for both q-groups: q = qt*128 + w*32 + qg*16 + l15
  ushort8 qf[2][2];
#pragma unroll
  for (int qg = 0; qg < 2; ++qg) {
    const size_t qrg = base + (size_t)(qt * 128 + w * 32 + qg * 16 + l15) * 64;
    qf[qg][0] = *(const ushort8*)&Qb[qrg + lhi * 8];
    qf[qg][1] = *(const ushort8*)&Qb[qrg + 32 + lhi * 8];
  }
  float m_s[2] = {NEG_INF, NEG_INF}, l_s[2] = {0.f, 0.f};
  f32x4 o[2][4] = {};

  // prologue: stage tile 0 into buf 0
  {
#pragma unroll
    for (int it = 0; it < 2; ++it) {
      const int chunk = tid + it * 256;
      const int row = chunk >> 3, g = chunk & 7;
      const int sg = g ^ (row & 7);
      GLOAD_LDS16(Kb + base + (size_t)row * 64 + sg * 8, &Ks[0][chunk * 8]);
    }
#pragma unroll
    for (int it = 0; it < 2; ++it) {
      const int t0 = vt0b + it * 32;
      const ushort_t* vp = Vb + base + (size_t)t0 * 64 + vd0;
      u64_t a = *(const u64_t*)vp;
      u64_t c = *(const u64_t*)(vp + 64);
      us4 av = __builtin_bit_cast(us4, a);
      us4 cv = __builtin_bit_cast(us4, c);
#pragma unroll
      for (int i = 0; i < 4; ++i) {
        const int d = vd0 + i;
        const int scg = (t0 >> 3) ^ ((d >> 2) & 7);
        unsigned int wv = (unsigned int)av[i] | ((unsigned int)cv[i] << 16);
        *(unsigned int*)&Vt[0][d * 72 + scg * 8 + (t0 & 7)] = wv;
      }
    }
  }
  __syncthreads();

  for (int kt = 0; kt < nkt; ++kt) {
    const int cur = kt & 1, nxt = cur ^ 1;
    const bool pf = (kt + 1 < nkt);
    u64_t va[2], vc[2];
    if (pf) {
      const size_t tb = base + (size_t)(kt + 1) * 64 * 64;
#pragma unroll
      for (int it = 0; it < 2; ++it) {
        const int chunk = tid + it * 256;
        const int row = chunk >> 3, g = chunk & 7;
        const int sg = g ^ (row & 7);
        GLOAD_LDS16(Kb + tb + (size_t)row * 64 + sg * 8, &Ks[nxt][chunk * 8]);
      }
#pragma unroll
      for (int it = 0; it < 2; ++it) {
        const int t0 = vt0b + it * 32;
        const ushort_t* vp = Vb + tb + (size_t)t0 * 64 + vd0;
        va[it] = *(const u64_t*)vp;
        vc[it] = *(const u64_t*)(vp + 64);
      }
    }

    // S^T = mfma(K, Q): shared kb feeds both q-groups
    f32x4 s[2][4] = {};
#pragma unroll
    for (int kk = 0; kk < 2; ++kk) {
#pragma unroll
      for (int j = 0; j < 4; ++j) {
        const int g = (kk * 4 + lhi) ^ (l15 & 7);
        ushort8 kb = *(const ushort8*)&Ks[cur][(j * 16 + l15) * 64 + g * 8];
        s[0][j] = mfma16(kb, qf[0][kk], s[0][j]);
        s[1][j] = mfma16(kb, qf[1][kk], s[1][j]);
      }
    }

    // per q-group: mask + softmax + P pack
#pragma unroll
    for (int qg = 0; qg < 2; ++qg) {
      const int qrow = w * 32 + qg * 16 + l15;
      if (64 * kt + 63 > 128 * qt + w * 32 + qg * 16) {
        const int delta = 128 * qt + qrow - 64 * kt;
#pragma unroll
        for (int j = 0; j < 4; ++j)
#pragma unroll
          for (int r = 0; r < 4; ++r)
            if ((j * 16 + lhi * 4 + r) > delta) s[qg][j][r] = NEG_INF;
      }
      float pmax = s[qg][0][0];
#pragma unroll
      for (int j = 0; j < 4; ++j)
#pragma unroll
        for (int r = 0; r < 4; ++r) pmax = fmaxf(pmax, s[qg][j][r]);
      pmax = fmaxf(pmax, __shfl_xor(pmax, 16));
      pmax = fmaxf(pmax, __shfl_xor(pmax, 32));
      if (__any(pmax - m_s[qg] > 8.0f)) {
        const float mnew = fmaxf(m_s[qg], pmax);
        const float al = exp2v(m_s[qg] - mnew);
        m_s[qg] = mnew;
        l_s[qg] *= al;
#pragma unroll
        for (int df = 0; df < 4; ++df)
#pragma unroll
          for (int r = 0; r < 4; ++r) o[qg][df][r] *= al;
      }
      float rsum = 0.f;
#pragma unroll
      for (int j = 0; j < 4; ++j)
#pragma unroll
        for (int r = 0; r < 4; ++r) {
          const float pe = exp2v(s[qg][j][r] - m_s[qg]);
          s[qg][j][r] = pe;
          rsum += pe;
        }
      rsum += __shfl_xor(rsum, 16);
      rsum += __shfl_xor(rsum, 32);
      l_s[qg] += rsum;

      ushort_t* pq = myP + qg * 16 * 72;
#pragma unroll
      for (int j = 0; j < 4; ++j) {
        const unsigned int w0 = cvtpk(s[qg][j][0], s[qg][j][1]);
        const unsigned int w1 = cvtpk(s[qg][j][2], s[qg][j][3]);
        const u64_t dw = (u64_t)w0 | ((u64_t)w1 << 32);
        const int cg = j * 2 + (lhi >> 1);
        *(u64_t*)&pq[l15 * 72 + ((cg ^ swzP) << 3) + ((lhi & 1) << 2)] = dw;
      }
    }

    // O^T += mfma(V^T-frag, P^T-frag): shared vb feeds both q-groups
#pragma unroll
    for (int kk = 0; kk < 2; ++kk) {
      ushort8 pa0 = *(const ushort8*)&myP[l15 * 72 + (((kk * 4 + lhi) ^ swzP) << 3)];
      ushort8 pa1 = *(const ushort8*)&myP[16 * 72 + l15 * 72 + (((kk * 4 + lhi) ^ swzP) << 3)];
#pragma unroll
      for (int df = 0; df < 4; ++df) {
        const int r = df * 16 + l15;
        const int g = (kk * 4 + lhi) ^ ((r >> 2) & 7);
        ushort8 vb = *(const ushort8*)&Vt[cur][r * 72 + g * 8];
        o[0][df] = mfma16(vb, pa0, o[0][df]);
        o[1][df] = mfma16(vb, pa1, o[1][df]);
      }
    }

    // write-late: V^T for next tile
    if (pf) {
#pragma unroll
      for (int it = 0; it < 2; ++it) {
        const int t0 = vt0b + it * 32;
        us4 av = __builtin_bit_cast(us4, va[it]);
        us4 cv = __builtin_bit_cast(us4, vc[it]);
#pragma unroll
        for (int i = 0; i < 4; ++i) {
          const int d = vd0 + i;
          const int scg = (t0 >> 3) ^ ((d >> 2) & 7);
          unsigned int wv = (unsigned int)av[i] | ((unsigned int)cv[i] << 16);
          *(unsigned int*)&Vt[nxt][d * 72 + scg * 8 + (t0 & 7)] = wv;
        }
      }
    }
    __syncthreads();
  }

  // epilogue: lane holds O^T[d][q] per q-group
#pragma unroll
  for (int qg = 0; qg < 2; ++qg) {
    const float inv = 1.0f / l_s[qg];
    const size_t yrow =
        (size_t)(b * 2048 + qt * 128 + w * 32 + qg * 16 + l15) * 1024 + h * 64;
#pragma unroll
    for (int df = 0; df < 4; ++df) {
      us4 ov;
#pragma unroll
      for (int r = 0; r < 4; ++r) ov[r] = f2bf(o[qg][df][r] * inv);
      *(us4*)&Yb[yrow + df * 16 + lhi * 4] = ov;
    }
  }
}

// ---------------- launch ----------------

extern "C" void kernel_launch(void* const* d_in, const int* in_sizes, int n_in,
                              void* d_out, int out_size, void* d_ws, size_t ws_size,
                              hipStream_t stream) {
  const float* x      = (const float*)d_in[0];
  const float* W_kqv  = (const float*)d_in[1];
  const float* b_kqv  = (const float*)d_in[2];
  const float* W_proj = (const float*)d_in[3];
  const float* b_proj = (const float*)d_in[4];
  float* out  = (float*)d_out;          // [B,T,C] fp32
  float* outK = out + 4194304;          // [B,H,T,D] fp32
  float* outV = out + 8388608;          // [B,H,T,D] fp32

  char* ws = (char*)d_ws;
  ushort_t* Xb  = (ushort_t*)(ws);
  ushort_t* Wkt = (ushort_t*)(ws + ((size_t)8 << 20));
  ushort_t* Wpt = (ushort_t*)(ws + ((size_t)14 << 20));
  ushort_t* Qb  = (ushort_t*)(ws + ((size_t)16 << 20));
  ushort_t* Kb  = (ushort_t*)(ws + ((size_t)24 << 20));
  ushort_t* Vb  = (ushort_t*)(ws + ((size_t)32 << 20));
  ushort_t* Yb  = Xb;  // Xb dead after QKV GEMM

  prep_kernel<<<6144, 256, 0, stream>>>(x, W_kqv, W_proj, Xb, Wkt, Wpt);
  gemm_bt_kernel<<<dim3(24, 32), 256, 0, stream>>>(
      Xb, Wkt, b_kqv, nullptr, outK, outV, Qb, Kb, Vb, 4096, 3072, 1024, 1);
  attn_kernel<<<512, 256, 0, stream>>>(Qb, Kb, Vb, Yb);
  gemm_bt64_kernel<<<dim3(8, 64), 256, 0, stream>>>(
      Yb, Wpt, b_proj, out, 4096, 1024, 1024);
}

// Round 18
// 107.287 us; speedup vs baseline: 1.1586x; 1.1586x over previous
//
#include <hip/hip_runtime.h>

// Workspace layout (40 MB total):
//   [0,  8M)  Xb  bf16 [4096][1024]   (reused as Yb after QKV GEMM)
//   [8, 14M)  Wkqv_t bf16 [3072][1024]
//   [14,16M)  Wproj_t bf16 [1024][1024]
//   [16,24M)  Qb bf16 [B,H,T,D]  (pre-scaled by 0.125*log2e)
//   [24,32M)  Kb bf16 [B,H,T,D]
//   [32,40M)  Vb bf16 [B,H,T,D]

#define DEVI __device__ __forceinline__

typedef unsigned short ushort_t;
typedef unsigned long long u64_t;
typedef __attribute__((ext_vector_type(4))) unsigned short us4;
typedef __attribute__((ext_vector_type(8))) unsigned short ushort8;
typedef __attribute__((ext_vector_type(4))) float f32x4;
typedef __attribute__((ext_vector_type(8))) __bf16 bf16x8;

DEVI unsigned short f2bf(float f) {
  union { float f; unsigned int u; } c; c.f = f;
  unsigned int u = c.u;
  unsigned int r = (u + 0x7FFFu + ((u >> 16) & 1u)) >> 16;
  return (unsigned short)r;
}

// exp2 via raw v_exp_f32 (1 VALU trans op; s_nop covers the RAW hazard)
DEVI float exp2v(float x) {
  float r;
  asm("v_exp_f32 %0, %1\n\ts_nop 0" : "=v"(r) : "v"(x));
  return r;
}

// pack 2 fp32 -> 2 bf16 (RNE) in one instruction
DEVI unsigned int cvtpk(float lo, float hi) {
  unsigned int r;
  asm("v_cvt_pk_bf16_f32 %0, %1, %2" : "=v"(r) : "v"(lo), "v"(hi));
  return r;
}

DEVI f32x4 mfma16(ushort8 a, ushort8 b, f32x4 c) {
  return __builtin_amdgcn_mfma_f32_16x16x32_bf16(
      __builtin_bit_cast(bf16x8, a), __builtin_bit_cast(bf16x8, b), c, 0, 0, 0);
}

typedef const __attribute__((address_space(1))) void* gptr_t;
typedef __attribute__((address_space(3))) void* lptr_t;
#define GLOAD_LDS16(g, l) \
  __builtin_amdgcn_global_load_lds((gptr_t)(g), (lptr_t)(l), 16, 0, 0)

DEVI void bar() {
  asm volatile("" ::: "memory");
  __builtin_amdgcn_s_barrier();
  asm volatile("" ::: "memory");
}
#define VMCNT(n) asm volatile("s_waitcnt vmcnt(" #n ")" ::: "memory")
#define LGKM0 asm volatile("s_waitcnt lgkmcnt(0)" ::: "memory")

// ---------------- fused prep kernel ----------------
// blocks [0,2048): cast x -> Xb (bf16)
// blocks [2048,5120): transpose+cast W_kqv -> Wkt [3072][1024]
// blocks [5120,6144): transpose+cast W_proj -> Wpt [1024][1024]

__global__ void prep_kernel(const float* __restrict__ x,
                            const float* __restrict__ Wk,
                            const float* __restrict__ Wp,
                            ushort_t* __restrict__ Xb,
                            ushort_t* __restrict__ Wkt,
                            ushort_t* __restrict__ Wpt) {
  __shared__ float tile[32][33];
  const int id = blockIdx.x, tid = threadIdx.x;
  if (id < 2048) {
    const int i = id * 256 + tid;
    const f32x4* p = (const f32x4*)x;
    f32x4 a = p[2 * i], b = p[2 * i + 1];
    ushort8 o;
    o[0] = f2bf(a[0]); o[1] = f2bf(a[1]); o[2] = f2bf(a[2]); o[3] = f2bf(a[3]);
    o[4] = f2bf(b[0]); o[5] = f2bf(b[1]); o[6] = f2bf(b[2]); o[7] = f2bf(b[3]);
    ((ushort8*)Xb)[i] = o;
    return;
  }
  const float* in;
  ushort_t* outp;
  int R = 1024, Cin, bx, by;
  if (id < 5120) {
    const int jid = id - 2048;
    bx = jid % 96; by = jid / 96; in = Wk; outp = Wkt; Cin = 3072;
  } else {
    const int jid = id - 5120;
    bx = jid % 32; by = jid / 32; in = Wp; outp = Wpt; Cin = 1024;
  }
  const int c0 = bx * 32, r0 = by * 32;
  const int tx = tid & 31, ty = tid >> 5;
#pragma unroll
  for (int it = 0; it < 4; ++it)
    tile[ty + it * 8][tx] = in[(size_t)(r0 + ty + it * 8) * Cin + c0 + tx];
  __syncthreads();
#pragma unroll
  for (int it = 0; it < 4; ++it)
    outp[(size_t)(c0 + ty + it * 8) * R + r0 + tx] = f2bf(tile[tx][ty + it * 8]);
}

// ---------------- QKV GEMM: 128x128, m97 structure ----------------
// XCD mapping: by-fast chunked -> per-XCD working set L2-resident.

__global__ __launch_bounds__(256) void gemm_bt_kernel(
    const ushort_t* __restrict__ A, const ushort_t* __restrict__ Bt,
    const float* __restrict__ bias, float* __restrict__ outF,
    float* __restrict__ outK, float* __restrict__ outV,
    ushort_t* __restrict__ Qb, ushort_t* __restrict__ Kb, ushort_t* __restrict__ Vb,
    int M, int N, int K, int mode) {
  __shared__ __align__(16) ushort_t As[128 * 64];
  __shared__ __align__(16) ushort_t Bs[128 * 64];
  const int tid = threadIdx.x;
  const int w = tid >> 6, lane = tid & 63;
  const int wr = w >> 1, wc = w & 1;
  const int nby = gridDim.y;
  const int chy = nby >> 3;
  const int orig = blockIdx.x + gridDim.x * blockIdx.y;
  const int xcd = orig & 7, idx = orig >> 3;
  const int by = xcd * chy + (idx % chy);
  const int bx = idx / chy;
  const int m0 = by * 128, n0 = bx * 128;
  const int l15 = lane & 15, lhi = lane >> 4;
  const int rowA = lane >> 3;
  const int sgc = (((lane & 7) ^ ((lane >> 3) & 7)) << 3);

  f32x4 acc[4][4] = {};

  const int nk = K >> 6;
  for (int kt = 0; kt < nk; ++kt) {
    const size_t k0 = (size_t)kt << 6;
    if (kt) bar();
#pragma unroll
    for (int it = 0; it < 4; ++it) {
      const int rbase = (w * 4 + it) * 8;
      GLOAD_LDS16(A + (size_t)(m0 + rbase + rowA) * K + k0 + sgc, &As[rbase * 64]);
      GLOAD_LDS16(Bt + (size_t)(n0 + rbase + rowA) * K + k0 + sgc, &Bs[rbase * 64]);
    }
    VMCNT(0);
    bar();
#pragma unroll
    for (int kk = 0; kk < 2; ++kk) {
      const int gof = (((kk * 4 + lhi) ^ (l15 & 7)) << 3);
      ushort8 a[4], b[4];
#pragma unroll
      for (int i = 0; i < 4; ++i)
        a[i] = *(const ushort8*)&As[(wr * 64 + i * 16 + l15) * 64 + gof];
#pragma unroll
      for (int j = 0; j < 4; ++j)
        b[j] = *(const ushort8*)&Bs[(wc * 64 + j * 16 + l15) * 64 + gof];
#pragma unroll
      for (int i = 0; i < 4; ++i)
#pragma unroll
        for (int j = 0; j < 4; ++j) acc[i][j] = mfma16(a[i], b[j], acc[i][j]);
    }
  }

  const float QSCALE = 0.18033688011112042f;  // 0.125 * log2(e)
#pragma unroll
  for (int i = 0; i < 4; ++i) {
#pragma unroll
    for (int j = 0; j < 4; ++j) {
      const int nn = n0 + wc * 64 + j * 16 + l15;
      const float bv = bias[nn];
#pragma unroll
      for (int r = 0; r < 4; ++r) {
        const int mm = m0 + wr * 64 + i * 16 + lhi * 4 + r;
        const float v = acc[i][j][r] + bv;
        if (mode == 0) {
          outF[(size_t)mm * N + nn] = v;
        } else {
          const int bb = mm >> 11, t = mm & 2047;
          const int c = nn & 1023, h = c >> 6, d = c & 63;
          const size_t idx2 = ((size_t)(bb * 16 + h) * 2048 + t) * 64 + d;
          const int sec = nn >> 10;
          if (sec == 0) {
            Qb[idx2] = f2bf(v * QSCALE);
          } else if (sec == 1) {
            outK[idx2] = v; Kb[idx2] = f2bf(v);
          } else {
            outV[idx2] = v; Vb[idx2] = f2bf(v);
          }
        }
      }
    }
  }
}

// ---------------- proj GEMM: 64x128 tiles, same chunked XCD mapping ----------------

__global__ __launch_bounds__(256) void gemm_bt64_kernel(
    const ushort_t* __restrict__ A, const ushort_t* __restrict__ Bt,
    const float* __restrict__ bias, float* __restrict__ outF,
    int M, int N, int K) {
  __shared__ __align__(16) ushort_t As[64 * 64];
  __shared__ __align__(16) ushort_t Bs[128 * 64];
  const int tid = threadIdx.x;
  const int w = tid >> 6, lane = tid & 63;
  const int wr = w >> 1, wc = w & 1;
  const int nby = gridDim.y;
  const int chy = nby >> 3;
  const int orig = blockIdx.x + gridDim.x * blockIdx.y;
  const int xcd = orig & 7, idx = orig >> 3;
  const int by = xcd * chy + (idx % chy);
  const int bx = idx / chy;
  const int m0 = by * 64, n0 = bx * 128;
  const int l15 = lane & 15, lhi = lane >> 4;
  const int rowA = lane >> 3;
  const int sgc = (((lane & 7) ^ ((lane >> 3) & 7)) << 3);

  f32x4 acc[2][4] = {};

  const int nk = K >> 6;
  for (int kt = 0; kt < nk; ++kt) {
    const size_t k0 = (size_t)kt << 6;
    if (kt) bar();
#pragma unroll
    for (int it = 0; it < 2; ++it) {
      const int rbase = (w * 2 + it) * 8;  // A: 64 rows
      GLOAD_LDS16(A + (size_t)(m0 + rbase + rowA) * K + k0 + sgc, &As[rbase * 64]);
    }
#pragma unroll
    for (int it = 0; it < 4; ++it) {
      const int rbase = (w * 4 + it) * 8;  // B: 128 rows
      GLOAD_LDS16(Bt + (size_t)(n0 + rbase + rowA) * K + k0 + sgc, &Bs[rbase * 64]);
    }
    VMCNT(0);
    bar();
#pragma unroll
    for (int kk = 0; kk < 2; ++kk) {
      const int gof = (((kk * 4 + lhi) ^ (l15 & 7)) << 3);
      ushort8 a[2], b[4];
#pragma unroll
      for (int i = 0; i < 2; ++i)
        a[i] = *(const ushort8*)&As[(wr * 32 + i * 16 + l15) * 64 + gof];
#pragma unroll
      for (int j = 0; j < 4; ++j)
        b[j] = *(const ushort8*)&Bs[(wc * 64 + j * 16 + l15) * 64 + gof];
#pragma unroll
      for (int i = 0; i < 2; ++i)
#pragma unroll
        for (int j = 0; j < 4; ++j) acc[i][j] = mfma16(a[i], b[j], acc[i][j]);
    }
  }

#pragma unroll
  for (int i = 0; i < 2; ++i) {
#pragma unroll
    for (int j = 0; j < 4; ++j) {
      const int nn = n0 + wc * 64 + j * 16 + l15;
      const float bv = bias[nn];
#pragma unroll
      for (int r = 0; r < 4; ++r) {
        const int mm = m0 + wr * 32 + i * 16 + lhi * 4 + r;
        outF[(size_t)mm * N + nn] = acc[i][j][r] + bv;
      }
    }
  }
}

// ---------------- flash attention: 8 waves, 128-row Q-tile, 2-deep pipeline ----
// Structure = round-16 (proven 49.7us) + T4 counted vmcnt:
//   K triple-buffered in LDS (3x8KB), V regs double-buffered; tile t+2's
//   3 VMEM ops (1 gload_lds K + 2 V b64 loads) issued at step t and left IN
//   FLIGHT across the barrier via s_waitcnt vmcnt(3); raw s_barrier with
//   explicit lgkmcnt(0) (no compiler vmcnt(0) drain anywhere in the loop).
// Grid 512 x 512 threads, XCD-pinned, balanced-pair dispatch (r16).

__global__ __launch_bounds__(512) void attn_kernel(
    const ushort_t* __restrict__ Qb, const ushort_t* __restrict__ Kb,
    const ushort_t* __restrict__ Vb, ushort_t* __restrict__ Yb) {
  __shared__ __align__(16) ushort_t Ks[3 * 64 * 64];  // K [t][d], chunk-swizzled, 3 bufs
  __shared__ __align__(16) ushort_t Vt[2][64 * 72];   // V^T [d][t], swizzled
  __shared__ __align__(16) ushort_t Pl[8 * 16 * 72];  // per-wave P^T' [q][t], swizzled
  const int id = blockIdx.x;
  const int xcd = id & 7;
  int qt, bh;
  if (id < 256) {
    const int j = id >> 3;
    bh = xcd + 8 * (j & 3);
    qt = 8 + (j >> 2);                // 8..15
  } else {
    const int j = (id - 256) >> 3;
    bh = xcd + 8 * (j & 3);
    qt = 7 - (j >> 2);                // 7..0
  }
  const int b = bh >> 4, h = bh & 15;
  const int tid = threadIdx.x, w = tid >> 6, lane = tid & 63;
  const int l15 = lane & 15, lhi = lane >> 4;
  const int swzP = 2 * (l15 & 3);
  const size_t base = (size_t)bh * 2048 * 64;
  const float NEG_INF = -__builtin_inff();
  ushort_t* myP = &Pl[w * 16 * 72];

  // K staging: one 16B chunk per thread (512 chunks = 64x64 tile)
  const int krow = tid >> 3, kg = tid & 7;
  const int ksg = kg ^ (krow & 7);
  // V staging: rows vt0, vt0+1 x 4 d's per thread
  const int vd0 = (tid & 15) * 4;
  const int vt0 = (tid >> 4) * 2;

  const int nkt = 2 * qt + 2;       // >= 2 always
  const int qrow = w * 16 + l15;    // 0..127 within q-tile

  // Q fragments (B-operand)
  ushort8 qf[2];
  {
    const size_t qrg = base + (size_t)(qt * 128 + qrow) * 64;
    qf[0] = *(const ushort8*)&Qb[qrg + lhi * 8];
    qf[1] = *(const ushort8*)&Qb[qrg + 32 + lhi * 8];
  }
  float m_s = NEG_INF, l_s = 0.f;
  f32x4 o[4] = {};

  u64_t vaA, vcA, vaB, vcB;  // V reg sets: set parity == tile parity

  // prologue: issue tiles 0 (->Ks[0], set A) and 1 (->Ks[1], set B);
  // drain tile 0 (vmcnt(3) leaves tile 1's 3 ops in flight); write Vt[0].
  {
    GLOAD_LDS16(Kb + base + (size_t)krow * 64 + ksg * 8, &Ks[tid * 8]);
    const ushort_t* vp0 = Vb + base + (size_t)vt0 * 64 + vd0;
    vaA = *(const u64_t*)vp0;
    vcA = *(const u64_t*)(vp0 + 64);
    GLOAD_LDS16(Kb + base + 4096 + (size_t)krow * 64 + ksg * 8,
                &Ks[4096 + tid * 8]);
    const ushort_t* vp1 = Vb + base + 4096 + (size_t)vt0 * 64 + vd0;
    vaB = *(const u64_t*)vp1;
    vcB = *(const u64_t*)(vp1 + 64);
    VMCNT(3);
    us4 av = __builtin_bit_cast(us4, vaA), cv = __builtin_bit_cast(us4, vcA);
#pragma unroll
    for (int i = 0; i < 4; ++i) {
      const int d = vd0 + i;
      const int scg = (vt0 >> 3) ^ ((d >> 3) & 7);
      *(unsigned int*)&Vt[0][d * 72 + scg * 8 + (vt0 & 7)] =
          (unsigned int)av[i] | ((unsigned int)cv[i] << 16);
    }
    LGKM0;
    bar();
  }

  // step: fill set (fa,fc) <- tile t+2; write set (wa,wc) holds tile t+1.
  auto step = [&](int t, int kr, int kf, int vtR,
                  u64_t& fa, u64_t& fc, u64_t& wa, u64_t& wc)
      __attribute__((always_inline)) {
    const bool issue = (t + 2 < nkt);
    if (issue) {
      const size_t tb = base + (size_t)(t + 2) * 4096;
      GLOAD_LDS16(Kb + tb + (size_t)krow * 64 + ksg * 8, &Ks[kf + tid * 8]);
      const ushort_t* vp = Vb + tb + (size_t)vt0 * 64 + vd0;
      fa = *(const u64_t*)vp;
      fc = *(const u64_t*)(vp + 64);
    }

    // S^T = mfma(K, Q)
    f32x4 s[4] = {};
#pragma unroll
    for (int kk = 0; kk < 2; ++kk) {
#pragma unroll
      for (int j = 0; j < 4; ++j) {
        const int g = (kk * 4 + lhi) ^ (l15 & 7);
        ushort8 kb = *(const ushort8*)&Ks[kr + (j * 16 + l15) * 64 + g * 8];
        s[j] = mfma16(kb, qf[kk], s[j]);
      }
    }
    // causal mask; S already in exp2 domain
    if (64 * t + 63 > 128 * qt + w * 16) {
      const int delta = 128 * qt + qrow - 64 * t;
#pragma unroll
      for (int j = 0; j < 4; ++j)
#pragma unroll
        for (int r = 0; r < 4; ++r)
          if ((j * 16 + lhi * 4 + r) > delta) s[j][r] = NEG_INF;
    }

    // in-lane softmax (r16 verbatim)
    float pmax = s[0][0];
#pragma unroll
    for (int j = 0; j < 4; ++j)
#pragma unroll
      for (int r = 0; r < 4; ++r) pmax = fmaxf(pmax, s[j][r]);
    pmax = fmaxf(pmax, __shfl_xor(pmax, 16));
    pmax = fmaxf(pmax, __shfl_xor(pmax, 32));
    if (__any(pmax - m_s > 8.0f)) {
      const float mnew = fmaxf(m_s, pmax);
      const float al = exp2v(m_s - mnew);
      m_s = mnew;
      l_s *= al;
#pragma unroll
      for (int df = 0; df < 4; ++df)
#pragma unroll
        for (int r = 0; r < 4; ++r) o[df][r] *= al;
    }
    float rsum = 0.f;
#pragma unroll
    for (int j = 0; j < 4; ++j)
#pragma unroll
      for (int r = 0; r < 4; ++r) {
        const float pe = exp2v(s[j][r] - m_s);
        s[j][r] = pe;
        rsum += pe;
      }
    rsum += __shfl_xor(rsum, 16);
    rsum += __shfl_xor(rsum, 32);
    l_s += rsum;

    // P^T pack -> LDS (wave-private, swizzled b64 writes)
#pragma unroll
    for (int j = 0; j < 4; ++j) {
      const unsigned int w0 = cvtpk(s[j][0], s[j][1]);
      const unsigned int w1 = cvtpk(s[j][2], s[j][3]);
      const u64_t dw = (u64_t)w0 | ((u64_t)w1 << 32);
      const int cg = j * 2 + (lhi >> 1);
      *(u64_t*)&myP[l15 * 72 + ((cg ^ swzP) << 3) + ((lhi & 1) << 2)] = dw;
    }

    // O^T += mfma(V^T-frag, P^T-frag)
#pragma unroll
    for (int kk = 0; kk < 2; ++kk) {
      ushort8 pa = *(const ushort8*)&myP[l15 * 72 + (((kk * 4 + lhi) ^ swzP) << 3)];
#pragma unroll
      for (int df = 0; df < 4; ++df) {
        const int r = df * 16 + l15;
        const int g = (kk * 4 + lhi) ^ ((r >> 3) & 7);
        ushort8 vb = *(const ushort8*)&Vt[vtR][r * 72 + g * 8];
        o[df] = mfma16(vb, pa, o[df]);
      }
    }

    // counted drain: tile t+1's 3 ops landed, tile t+2's 3 stay in flight
    if (issue) {
      VMCNT(3);
    } else {
      VMCNT(0);
    }
    if (t + 1 < nkt) {  // write-late: V^T(t+1) into the other Vt buffer
      us4 av = __builtin_bit_cast(us4, wa), cv = __builtin_bit_cast(us4, wc);
#pragma unroll
      for (int i = 0; i < 4; ++i) {
        const int d = vd0 + i;
        const int scg = (vt0 >> 3) ^ ((d >> 3) & 7);
        *(unsigned int*)&Vt[vtR ^ 1][d * 72 + scg * 8 + (vt0 & 7)] =
            (unsigned int)av[i] | ((unsigned int)cv[i] << 16);
      }
    }
    LGKM0;
    bar();
  };

  int t = 0, kr = 0, kf = 8192;
  for (;;) {
    step(t, kr, kf, 0, vaA, vcA, vaB, vcB);  // even: fill A (t+2 even), write B
    if (++t == nkt) break;
    kr = (kr == 8192) ? 0 : kr + 4096;
    kf = (kf == 8192) ? 0 : kf + 4096;
    step(t, kr, kf, 1, vaB, vcB, vaA, vcA);  // odd: fill B, write A
    if (++t == nkt) break;
    kr = (kr == 8192) ? 0 : kr + 4096;
    kf = (kf == 8192) ? 0 : kf + 4096;
  }

  // epilogue: lane holds O^T[d = df*16+lhi*4+r][q]
  const float inv = 1.0f / l_s;
  const size_t yrow = (size_t)(b * 2048 + qt * 128 + qrow) * 1024 + h * 64;
#pragma unroll
  for (int df = 0; df < 4; ++df) {
    us4 ov;
#pragma unroll
    for (int r = 0; r < 4; ++r) ov[r] = f2bf(o[df][r] * inv);
    *(us4*)&Yb[yrow + df * 16 + lhi * 4] = ov;
  }
}

// ---------------- launch ----------------

extern "C" void kernel_launch(void* const* d_in, const int* in_sizes, int n_in,
                              void* d_out, int out_size, void* d_ws, size_t ws_size,
                              hipStream_t stream) {
  const float* x      = (const float*)d_in[0];
  const float* W_kqv  = (const float*)d_in[1];
  const float* b_kqv  = (const float*)d_in[2];
  const float* W_proj = (const float*)d_in[3];
  const float* b_proj = (const float*)d_in[4];
  float* out  = (float*)d_out;          // [B,T,C] fp32
  float* outK = out + 4194304;          // [B,H,T,D] fp32
  float* outV = out + 8388608;          // [B,H,T,D] fp32

  char* ws = (char*)d_ws;
  ushort_t* Xb  = (ushort_t*)(ws);
  ushort_t* Wkt = (ushort_t*)(ws + ((size_t)8 << 20));
  ushort_t* Wpt = (ushort_t*)(ws + ((size_t)14 << 20));
  ushort_t* Qb  = (ushort_t*)(ws + ((size_t)16 << 20));
  ushort_t* Kb  = (ushort_t*)(ws + ((size_t)24 << 20));
  ushort_t* Vb  = (ushort_t*)(ws + ((size_t)32 << 20));
  ushort_t* Yb  = Xb;  // Xb dead after QKV GEMM

  prep_kernel<<<6144, 256, 0, stream>>>(x, W_kqv, W_proj, Xb, Wkt, Wpt);
  gemm_bt_kernel<<<dim3(24, 32), 256, 0, stream>>>(
      Xb, Wkt, b_kqv, nullptr, outK, outV, Qb, Kb, Vb, 4096, 3072, 1024, 1);
  attn_kernel<<<512, 512, 0, stream>>>(Qb, Kb, Vb, Yb);
  gemm_bt64_kernel<<<dim3(8, 64), 256, 0, stream>>>(
      Yb, Wpt, b_proj, out, 4096, 1024, 1024);
}